// Round 3
// baseline (934.150 us; speedup 1.0000x reference)
//
#include <hip/hip_runtime.h>

typedef _Float16 f16;
typedef _Float16 f16x8 __attribute__((ext_vector_type(8)));
typedef _Float16 f16x4 __attribute__((ext_vector_type(4)));
typedef float f32x4 __attribute__((ext_vector_type(4)));

#define B_ 512
#define L_ 512
#define Cc_ 64
#define Ct_ 16
#define Co_ 8
#define H_ 128
#define IN_ 88
#define KP 96       // padded K for MFMA
#define G3 384      // 3*H
#define R_ 16       // batch rows per scan block

// ---------------- K0: pad+convert W_ih (384x88 f32) -> (384x96 f16) ----------------
__global__ void k_prep_wih(const float* __restrict__ Wih, f16* __restrict__ WihH) {
    int idx = blockIdx.x * 256 + threadIdx.x;   // 384*96 = 36864 total
    if (idx >= G3 * KP) return;
    int n = idx / KP, k = idx % KP;
    WihH[idx] = (k < IN_) ? (f16)Wih[n * IN_ + k] : (f16)0.f;
}

// ---------------- K1: time-norm (mean/var over L per (b,ch)) + concat -> f16 (B*L x 96) ----
__global__ __launch_bounds__(256) void k_norm(
        const float* __restrict__ cov, const float* __restrict__ tr, const float* __restrict__ oc,
        const float* __restrict__ g_t, const float* __restrict__ bt,
        const float* __restrict__ g_o, const float* __restrict__ bo,
        const float* __restrict__ g_c, const float* __restrict__ bc,
        f16* __restrict__ inpH) {
    int b = blockIdx.x, t = threadIdx.x;
    __shared__ float ps[256], ps2[256];
    __shared__ float sc[88], sh[88];   // concat order: t[0:16), o[16:24), c[24:88)

    { // covariates, C=64, 4 l-groups
        int c = t & 63, lg = t >> 6;
        const float* p = cov + (size_t)b * L_ * Cc_ + c;
        float s = 0.f, s2 = 0.f;
        for (int i = lg; i < L_; i += 4) { float v = p[(size_t)i * Cc_]; s += v; s2 += v * v; }
        ps[t] = s; ps2[t] = s2; __syncthreads();
        if (t < 64) {
            float S = 0.f, S2 = 0.f;
            for (int g = 0; g < 4; g++) { S += ps[t + 64 * g]; S2 += ps2[t + 64 * g]; }
            float m = S * (1.f / L_), v = S2 * (1.f / L_) - m * m;
            float inv = rsqrtf(v + 1e-5f);
            float gg = g_c[t] * inv;
            sc[24 + t] = gg; sh[24 + t] = bc[t] - m * gg;
        }
        __syncthreads();
    }
    { // treatments, C=16, 16 l-groups
        int c = t & 15, lg = t >> 4;
        const float* p = tr + (size_t)b * L_ * Ct_ + c;
        float s = 0.f, s2 = 0.f;
        for (int i = lg; i < L_; i += 16) { float v = p[(size_t)i * Ct_]; s += v; s2 += v * v; }
        ps[t] = s; ps2[t] = s2; __syncthreads();
        if (t < 16) {
            float S = 0.f, S2 = 0.f;
            for (int g = 0; g < 16; g++) { S += ps[t + 16 * g]; S2 += ps2[t + 16 * g]; }
            float m = S * (1.f / L_), v = S2 * (1.f / L_) - m * m;
            float inv = rsqrtf(v + 1e-5f);
            float gg = g_t[t] * inv;
            sc[t] = gg; sh[t] = bt[t] - m * gg;
        }
        __syncthreads();
    }
    { // outcomes, C=8, 32 l-groups
        int c = t & 7, lg = t >> 3;
        const float* p = oc + (size_t)b * L_ * Co_ + c;
        float s = 0.f, s2 = 0.f;
        for (int i = lg; i < L_; i += 32) { float v = p[(size_t)i * Co_]; s += v; s2 += v * v; }
        ps[t] = s; ps2[t] = s2; __syncthreads();
        if (t < 8) {
            float S = 0.f, S2 = 0.f;
            for (int g = 0; g < 32; g++) { S += ps[t + 8 * g]; S2 += ps2[t + 8 * g]; }
            float m = S * (1.f / L_), v = S2 * (1.f / L_) - m * m;
            float inv = rsqrtf(v + 1e-5f);
            float gg = g_o[t] * inv;
            sc[16 + t] = gg; sh[16 + t] = bo[t] - m * gg;
        }
        __syncthreads();
    }
    // phase B: normalize + concat + pad, write f16
    f16* outp = inpH + (size_t)b * L_ * KP;
    for (int idx = t; idx < L_ * KP; idx += 256) {
        int l = idx / KP, cc = idx % KP;
        float y = 0.f;
        if (cc < 88) {
            float x;
            if (cc < 16)      x = tr[((size_t)b * L_ + l) * Ct_ + cc];
            else if (cc < 24) x = oc[((size_t)b * L_ + l) * Co_ + (cc - 16)];
            else              x = cov[((size_t)b * L_ + l) * Cc_ + (cc - 24)];
            y = x * sc[cc] + sh[cc];
        }
        outp[idx] = (f16)y;
    }
}

// ---------------- K2: gi = inp @ W_ih^T + b_ih, f16 MFMA, output f16 (M x 384) ----------
__global__ __launch_bounds__(256) void k_gemm(
        const f16* __restrict__ A, const f16* __restrict__ W,
        const float* __restrict__ bih, f16* __restrict__ gi) {
    int lane = threadIdx.x & 63, wave = threadIdx.x >> 6;
    int m0 = blockIdx.x * 64 + wave * 16;
    int r = lane & 15, q = lane >> 4;

    const f16* ap = A + (size_t)(m0 + r) * KP + q * 8;
    f16x8 a0 = *(const f16x8*)(ap);
    f16x8 a1 = *(const f16x8*)(ap + 32);
    f16x8 a2 = *(const f16x8*)(ap + 64);

    for (int n0 = 0; n0 < 24; n0++) {
        const f16* bp = W + (size_t)(n0 * 16 + r) * KP + q * 8;
        f16x8 b0 = *(const f16x8*)(bp);
        f16x8 b1 = *(const f16x8*)(bp + 32);
        f16x8 b2 = *(const f16x8*)(bp + 64);
        f32x4 acc = {0.f, 0.f, 0.f, 0.f};
        acc = __builtin_amdgcn_mfma_f32_16x16x32_f16(a0, b0, acc, 0, 0, 0);
        acc = __builtin_amdgcn_mfma_f32_16x16x32_f16(a1, b1, acc, 0, 0, 0);
        acc = __builtin_amdgcn_mfma_f32_16x16x32_f16(a2, b2, acc, 0, 0, 0);
        int n = n0 * 16 + r;
        float bias = bih[n];
        f16* gp = gi + (size_t)(m0 + q * 4) * G3 + n;
        #pragma unroll
        for (int e = 0; e < 4; e++)
            gp[(size_t)e * G3] = (f16)(acc[e] + bias);
    }
}

// ---------------- K3: GRU scan via MFMA, schedule-fixed. 16 rows/block, 8 waves. -------
// Per step: [issue gi loads for l+1 FIRST (before any store -> no vmcnt entanglement,
// ~1.3 steps of latency coverage)] -> ds_read h (4x b128, XOR-swizzled) -> 12 MFMA ->
// gate VALU -> ds_write h_next -> f32x4 output stores -> barrier.
// Loop unrolled x2: static LDS buffers (hb0/hb1) and static gi reg ping-pong (E/O).
__global__ __launch_bounds__(512, 2) void k_scan_mfma(
        const f16* __restrict__ gi, const float* __restrict__ Whh, const float* __restrict__ bhh,
        float* __restrict__ outA, float* __restrict__ outB, int rowBase) {
    const int t = threadIdx.x;
    const int w = t >> 6;          // wave 0..7: owns hidden units [16w, 16w+16)
    const int lane = t & 63;
    const int c = lane & 15;       // batch row within tile
    const int q = lane >> 4;       // 0..3
    const int q8 = q * 8;
    const int lrow = blockIdx.x * R_ + c;       // local batch row (gi index)
    const int row  = rowBase + lrow;            // global batch row (output index)
    const int uD = 16 * w + q * 4;              // this lane's unit base in D

    __shared__ f16 hb0[R_ * H_];                // 4KB each, swizzled [b][k^((b&7)<<3)]
    __shared__ f16 hb1[R_ * H_];

    // persistent W_hh A-fragments: unit = 16w + c, k = q*8 + 32ks + j  (f32 -> f16)
    f16x8 WA[3][4];
    #pragma unroll
    for (int g = 0; g < 3; g++)
        #pragma unroll
        for (int ks = 0; ks < 4; ks++) {
            const float* wp = Whh + (size_t)(g * H_ + 16 * w + c) * H_ + q8 + 32 * ks;
            f16x8 v;
            #pragma unroll
            for (int j = 0; j < 8; j++) v[j] = (f16)wp[j];
            WA[g][ks] = v;
        }
    const float bR0 = bhh[0 * H_ + uD + 0], bR1 = bhh[0 * H_ + uD + 1],
                bR2 = bhh[0 * H_ + uD + 2], bR3 = bhh[0 * H_ + uD + 3];
    const float bZ0 = bhh[1 * H_ + uD + 0], bZ1 = bhh[1 * H_ + uD + 1],
                bZ2 = bhh[1 * H_ + uD + 2], bZ3 = bhh[1 * H_ + uD + 3];
    const float bN0 = bhh[2 * H_ + uD + 0], bN1 = bhh[2 * H_ + uD + 1],
                bN2 = bhh[2 * H_ + uD + 2], bN3 = bhh[2 * H_ + uD + 3];

    for (int i = t; i < R_ * H_; i += 512) hb0[i] = (f16)0.f;
    float hp0 = 0.f, hp1 = 0.f, hp2 = 0.f, hp3 = 0.f;

    // per-lane output pointer (bump by ostride each step)
    float* op; int ostride;
    if (uD < Co_) { op = outA + (size_t)row * L_ * Co_ + uD;               ostride = Co_; }
    else          { op = outB + (size_t)row * L_ * (H_ - Co_) + (uD - Co_); ostride = H_ - Co_; }

    const int swzm = (c & 7) << 3;              // XOR swizzle mask (f16 index bits 3..5)
    const f16* gp = gi + (size_t)lrow * L_ * G3 + uD;

    // preload gi[0] into E buffers
    f16x4 gRe = *(const f16x4*)(gp + 0 * H_);
    f16x4 gZe = *(const f16x4*)(gp + 1 * H_);
    f16x4 gNe = *(const f16x4*)(gp + 2 * H_);
    f16x4 gRo, gZo, gNo;

    __syncthreads();

#define GRU_STEP(HCUR, HNEXT, GR, GZ, GN)                                          \
    {                                                                               \
        f16x8 hB0 = *(const f16x8*)(HCUR + c * H_ + ((q8 +  0) ^ swzm));            \
        f16x8 hB1 = *(const f16x8*)(HCUR + c * H_ + ((q8 + 32) ^ swzm));            \
        f16x8 hB2 = *(const f16x8*)(HCUR + c * H_ + ((q8 + 64) ^ swzm));            \
        f16x8 hB3 = *(const f16x8*)(HCUR + c * H_ + ((q8 + 96) ^ swzm));            \
        f32x4 aR = {0.f,0.f,0.f,0.f}, aZ = {0.f,0.f,0.f,0.f}, aN = {0.f,0.f,0.f,0.f};\
        aR = __builtin_amdgcn_mfma_f32_16x16x32_f16(WA[0][0], hB0, aR, 0, 0, 0);    \
        aZ = __builtin_amdgcn_mfma_f32_16x16x32_f16(WA[1][0], hB0, aZ, 0, 0, 0);    \
        aN = __builtin_amdgcn_mfma_f32_16x16x32_f16(WA[2][0], hB0, aN, 0, 0, 0);    \
        aR = __builtin_amdgcn_mfma_f32_16x16x32_f16(WA[0][1], hB1, aR, 0, 0, 0);    \
        aZ = __builtin_amdgcn_mfma_f32_16x16x32_f16(WA[1][1], hB1, aZ, 0, 0, 0);    \
        aN = __builtin_amdgcn_mfma_f32_16x16x32_f16(WA[2][1], hB1, aN, 0, 0, 0);    \
        aR = __builtin_amdgcn_mfma_f32_16x16x32_f16(WA[0][2], hB2, aR, 0, 0, 0);    \
        aZ = __builtin_amdgcn_mfma_f32_16x16x32_f16(WA[1][2], hB2, aZ, 0, 0, 0);    \
        aN = __builtin_amdgcn_mfma_f32_16x16x32_f16(WA[2][2], hB2, aN, 0, 0, 0);    \
        aR = __builtin_amdgcn_mfma_f32_16x16x32_f16(WA[0][3], hB3, aR, 0, 0, 0);    \
        aZ = __builtin_amdgcn_mfma_f32_16x16x32_f16(WA[1][3], hB3, aZ, 0, 0, 0);    \
        aN = __builtin_amdgcn_mfma_f32_16x16x32_f16(WA[2][3], hB3, aN, 0, 0, 0);    \
        float rg0 = 1.f / (1.f + __expf(-(aR[0] + bR0 + (float)GR[0])));            \
        float rg1 = 1.f / (1.f + __expf(-(aR[1] + bR1 + (float)GR[1])));            \
        float rg2 = 1.f / (1.f + __expf(-(aR[2] + bR2 + (float)GR[2])));            \
        float rg3 = 1.f / (1.f + __expf(-(aR[3] + bR3 + (float)GR[3])));            \
        float zg0 = 1.f / (1.f + __expf(-(aZ[0] + bZ0 + (float)GZ[0])));            \
        float zg1 = 1.f / (1.f + __expf(-(aZ[1] + bZ1 + (float)GZ[1])));            \
        float zg2 = 1.f / (1.f + __expf(-(aZ[2] + bZ2 + (float)GZ[2])));            \
        float zg3 = 1.f / (1.f + __expf(-(aZ[3] + bZ3 + (float)GZ[3])));            \
        float ng0 = 2.f / (1.f + __expf(-2.f * ((float)GN[0] + rg0 * (aN[0] + bN0)))) - 1.f; \
        float ng1 = 2.f / (1.f + __expf(-2.f * ((float)GN[1] + rg1 * (aN[1] + bN1)))) - 1.f; \
        float ng2 = 2.f / (1.f + __expf(-2.f * ((float)GN[2] + rg2 * (aN[2] + bN2)))) - 1.f; \
        float ng3 = 2.f / (1.f + __expf(-2.f * ((float)GN[3] + rg3 * (aN[3] + bN3)))) - 1.f; \
        hp0 = ng0 + zg0 * (hp0 - ng0);                                              \
        hp1 = ng1 + zg1 * (hp1 - ng1);                                              \
        hp2 = ng2 + zg2 * (hp2 - ng2);                                              \
        hp3 = ng3 + zg3 * (hp3 - ng3);                                              \
        f16x4 hv16 = {(f16)hp0, (f16)hp1, (f16)hp2, (f16)hp3};                      \
        *(f16x4*)(HNEXT + c * H_ + (uD ^ swzm)) = hv16;                             \
        f32x4 hv32 = {hp0, hp1, hp2, hp3};                                          \
        *(f32x4*)op = hv32;                                                         \
        op += ostride;                                                              \
    }

    for (int l = 0; l < L_; l += 2) {
        // ---- even step l: read hb0, write hb1. Issue gi[l+1] loads FIRST. ----
        {
            const f16* gn = gp + (size_t)(l + 1) * G3;
            gRo = *(const f16x4*)(gn + 0 * H_);
            gZo = *(const f16x4*)(gn + 1 * H_);
            gNo = *(const f16x4*)(gn + 2 * H_);
        }
        GRU_STEP(hb0, hb1, gRe, gZe, gNe)
        __syncthreads();

        // ---- odd step l+1: read hb1, write hb0. Issue gi[l+2] loads FIRST. ----
        {
            int lp = (l + 2 < L_) ? (l + 2) : (L_ - 1);   // clamp: last reload unused
            const f16* gn = gp + (size_t)lp * G3;
            gRe = *(const f16x4*)(gn + 0 * H_);
            gZe = *(const f16x4*)(gn + 1 * H_);
            gNe = *(const f16x4*)(gn + 2 * H_);
        }
        GRU_STEP(hb1, hb0, gRo, gZo, gNo)
        __syncthreads();
    }
#undef GRU_STEP
}

// ---------------- launch ----------------
extern "C" void kernel_launch(void* const* d_in, const int* in_sizes, int n_in,
                              void* d_out, int out_size, void* d_ws, size_t ws_size,
                              hipStream_t stream) {
    (void)in_sizes; (void)n_in;
    const float* cov = (const float*)d_in[0];
    const float* tr  = (const float*)d_in[1];
    const float* oc  = (const float*)d_in[2];
    const float* Wih = (const float*)d_in[3];
    const float* Whh = (const float*)d_in[4];
    const float* bih = (const float*)d_in[5];
    const float* bhh = (const float*)d_in[6];
    const float* g_t = (const float*)d_in[7];
    const float* bt  = (const float*)d_in[8];
    const float* g_o = (const float*)d_in[9];
    const float* bo  = (const float*)d_in[10];
    const float* g_c = (const float*)d_in[11];
    const float* bc  = (const float*)d_in[12];

    float* outA = (float*)d_out;
    float* outB = (float*)d_out + (size_t)B_ * L_ * Co_;

    // workspace layout: [WihH f16 384x96 | pad to 128KB | giH f16 (M_split x 384)]
    f16* WihH = (f16*)d_ws;
    f16* giH  = (f16*)((char*)d_ws + 131072);

    // normalized f16 input lives at the TOP of d_out (dead before outputs reach it)
    size_t outBytes = (size_t)out_size * 4;
    size_t ihBytes  = (size_t)B_ * L_ * KP * 2;   // 50.3 MB
    f16* inpH = (f16*)((char*)d_out + (outBytes - ihBytes));

    // pick batch split so gi fits in ws
    int S = 8;
    const int cand[4] = {1, 2, 4, 8};
    for (int i = 0; i < 4; i++) {
        size_t need = 131072 + ((size_t)B_ / cand[i]) * L_ * G3 * 2;
        if (need <= ws_size) { S = cand[i]; break; }
    }
    int Bs = B_ / S;

    k_prep_wih<<<dim3(144), dim3(256), 0, stream>>>(Wih, WihH);
    k_norm<<<dim3(B_), dim3(256), 0, stream>>>(cov, tr, oc, g_t, bt, g_o, bo, g_c, bc, inpH);

    for (int s = 0; s < S; s++) {
        const f16* Asub = inpH + (size_t)s * Bs * L_ * KP;
        int Msub = Bs * L_;
        k_gemm<<<dim3(Msub / 64), dim3(256), 0, stream>>>(Asub, WihH, bih, giH);
        k_scan_mfma<<<dim3(Bs / R_), dim3(512), 0, stream>>>(giH, Whh, bhh, outA, outB, s * Bs);
    }
}

// Round 4
// 742.617 us; speedup vs baseline: 1.2579x; 1.2579x over previous
//
#include <hip/hip_runtime.h>

typedef _Float16 f16;
typedef _Float16 f16x8 __attribute__((ext_vector_type(8)));
typedef _Float16 f16x4 __attribute__((ext_vector_type(4)));
typedef float f32x4 __attribute__((ext_vector_type(4)));

#define B_ 512
#define L_ 512
#define Cc_ 64
#define Ct_ 16
#define Co_ 8
#define H_ 128
#define IN_ 88
#define KP 96       // padded K for MFMA
#define G3 384      // 3*H
#define R_ 16       // batch rows per scan block

#define L2E  1.44269504088896f   // log2(e)
#define L2E2 2.88539008177793f   // 2*log2(e)

// ---------------- K0: pad+convert W_ih -> f16, pre-scaled by L2E (r,z) / L2E2 (n) ------
__global__ void k_prep_wih(const float* __restrict__ Wih, f16* __restrict__ WihH) {
    int idx = blockIdx.x * 256 + threadIdx.x;   // 384*96 = 36864 total
    if (idx >= G3 * KP) return;
    int n = idx / KP, k = idx % KP;
    float s = (n < 256) ? L2E : L2E2;
    WihH[idx] = (k < IN_) ? (f16)(Wih[n * IN_ + k] * s) : (f16)0.f;
}

// ---------------- K1: time-norm (mean/var over L per (b,ch)) + concat -> f16 (B*L x 96) ----
__global__ __launch_bounds__(256) void k_norm(
        const float* __restrict__ cov, const float* __restrict__ tr, const float* __restrict__ oc,
        const float* __restrict__ g_t, const float* __restrict__ bt,
        const float* __restrict__ g_o, const float* __restrict__ bo,
        const float* __restrict__ g_c, const float* __restrict__ bc,
        f16* __restrict__ inpH) {
    int b = blockIdx.x, t = threadIdx.x;
    __shared__ float ps[256], ps2[256];
    __shared__ float sc[88], sh[88];   // concat order: t[0:16), o[16:24), c[24:88)

    { // covariates, C=64, 4 l-groups
        int c = t & 63, lg = t >> 6;
        const float* p = cov + (size_t)b * L_ * Cc_ + c;
        float s = 0.f, s2 = 0.f;
        for (int i = lg; i < L_; i += 4) { float v = p[(size_t)i * Cc_]; s += v; s2 += v * v; }
        ps[t] = s; ps2[t] = s2; __syncthreads();
        if (t < 64) {
            float S = 0.f, S2 = 0.f;
            for (int g = 0; g < 4; g++) { S += ps[t + 64 * g]; S2 += ps2[t + 64 * g]; }
            float m = S * (1.f / L_), v = S2 * (1.f / L_) - m * m;
            float inv = rsqrtf(v + 1e-5f);
            float gg = g_c[t] * inv;
            sc[24 + t] = gg; sh[24 + t] = bc[t] - m * gg;
        }
        __syncthreads();
    }
    { // treatments, C=16, 16 l-groups
        int c = t & 15, lg = t >> 4;
        const float* p = tr + (size_t)b * L_ * Ct_ + c;
        float s = 0.f, s2 = 0.f;
        for (int i = lg; i < L_; i += 16) { float v = p[(size_t)i * Ct_]; s += v; s2 += v * v; }
        ps[t] = s; ps2[t] = s2; __syncthreads();
        if (t < 16) {
            float S = 0.f, S2 = 0.f;
            for (int g = 0; g < 16; g++) { S += ps[t + 16 * g]; S2 += ps2[t + 16 * g]; }
            float m = S * (1.f / L_), v = S2 * (1.f / L_) - m * m;
            float inv = rsqrtf(v + 1e-5f);
            float gg = g_t[t] * inv;
            sc[t] = gg; sh[t] = bt[t] - m * gg;
        }
        __syncthreads();
    }
    { // outcomes, C=8, 32 l-groups
        int c = t & 7, lg = t >> 3;
        const float* p = oc + (size_t)b * L_ * Co_ + c;
        float s = 0.f, s2 = 0.f;
        for (int i = lg; i < L_; i += 32) { float v = p[(size_t)i * Co_]; s += v; s2 += v * v; }
        ps[t] = s; ps2[t] = s2; __syncthreads();
        if (t < 8) {
            float S = 0.f, S2 = 0.f;
            for (int g = 0; g < 32; g++) { S += ps[t + 8 * g]; S2 += ps2[t + 8 * g]; }
            float m = S * (1.f / L_), v = S2 * (1.f / L_) - m * m;
            float inv = rsqrtf(v + 1e-5f);
            float gg = g_o[t] * inv;
            sc[16 + t] = gg; sh[16 + t] = bo[t] - m * gg;
        }
        __syncthreads();
    }
    // phase B: normalize + concat + pad, write f16
    f16* outp = inpH + (size_t)b * L_ * KP;
    for (int idx = t; idx < L_ * KP; idx += 256) {
        int l = idx / KP, cc = idx % KP;
        float y = 0.f;
        if (cc < 88) {
            float x;
            if (cc < 16)      x = tr[((size_t)b * L_ + l) * Ct_ + cc];
            else if (cc < 24) x = oc[((size_t)b * L_ + l) * Co_ + (cc - 16)];
            else              x = cov[((size_t)b * L_ + l) * Cc_ + (cc - 24)];
            y = x * sc[cc] + sh[cc];
        }
        outp[idx] = (f16)y;
    }
}

// ---------------- K2: gi = inp @ W_ih'^T + bias', f16 MFMA, output f16 (M x 384) --------
// bias' folds b_ih (all gates) + b_hh (r,z only), pre-scaled like the weights.
__global__ __launch_bounds__(256) void k_gemm(
        const f16* __restrict__ A, const f16* __restrict__ W,
        const float* __restrict__ bih, const float* __restrict__ bhh,
        f16* __restrict__ gi) {
    int lane = threadIdx.x & 63, wave = threadIdx.x >> 6;
    int m0 = blockIdx.x * 64 + wave * 16;
    int r = lane & 15, q = lane >> 4;

    const f16* ap = A + (size_t)(m0 + r) * KP + q * 8;
    f16x8 a0 = *(const f16x8*)(ap);
    f16x8 a1 = *(const f16x8*)(ap + 32);
    f16x8 a2 = *(const f16x8*)(ap + 64);

    for (int n0 = 0; n0 < 24; n0++) {
        const f16* bp = W + (size_t)(n0 * 16 + r) * KP + q * 8;
        f16x8 b0 = *(const f16x8*)(bp);
        f16x8 b1 = *(const f16x8*)(bp + 32);
        f16x8 b2 = *(const f16x8*)(bp + 64);
        f32x4 acc = {0.f, 0.f, 0.f, 0.f};
        acc = __builtin_amdgcn_mfma_f32_16x16x32_f16(a0, b0, acc, 0, 0, 0);
        acc = __builtin_amdgcn_mfma_f32_16x16x32_f16(a1, b1, acc, 0, 0, 0);
        acc = __builtin_amdgcn_mfma_f32_16x16x32_f16(a2, b2, acc, 0, 0, 0);
        int n = n0 * 16 + r;
        float bias = (n < 256) ? (bih[n] + bhh[n]) * L2E : bih[n] * L2E2;
        f16* gp = gi + (size_t)(m0 + q * 4) * G3 + n;
        #pragma unroll
        for (int e = 0; e < 4; e++)
            gp[(size_t)e * G3] = (f16)(acc[e] + bias);
    }
}

// ---------------- K3: GRU scan via MFMA. 16 rows/block, 8 waves. ------------------------
// Per step: [stage-store h_out(l-1) coalesced from LDS] [gi(l+1) loads] [4 ds_read hB]
// [12 MFMA, C-init = gi (r,z) / b_hh (n)] [lean exp2-form gates] [ds_write h] [barrier].
__global__ __launch_bounds__(512, 2) void k_scan_mfma(
        const f16* __restrict__ gi, const float* __restrict__ Whh, const float* __restrict__ bhh,
        float* __restrict__ outA, float* __restrict__ outB, int rowBase) {
    const int t = threadIdx.x;
    const int w = t >> 6;          // wave 0..7: owns hidden units [16w, 16w+16)
    const int lane = t & 63;
    const int c = lane & 15;       // batch row within tile
    const int q = lane >> 4;       // 0..3
    const int q8 = q * 8;
    const int lrow = blockIdx.x * R_ + c;       // local batch row (gi index)
    const int uD = 16 * w + q * 4;              // this lane's unit base in D

    __shared__ f16 hb0[R_ * H_];                // 4KB each, swizzled [b][k^((b&7)<<3)]
    __shared__ f16 hb1[R_ * H_];

    // persistent W_hh A-fragments: unit = 16w + c, k = q*8 + 32ks + j  (f32 -> f16, scaled)
    f16x8 WA[3][4];
    #pragma unroll
    for (int g = 0; g < 3; g++) {
        float s = (g < 2) ? L2E : L2E2;
        #pragma unroll
        for (int ks = 0; ks < 4; ks++) {
            const float* wp = Whh + (size_t)(g * H_ + 16 * w + c) * H_ + q8 + 32 * ks;
            f16x8 v;
            #pragma unroll
            for (int j = 0; j < 8; j++) v[j] = (f16)(wp[j] * s);
            WA[g][ks] = v;
        }
    }
    // n-gate b_hh, pre-scaled — becomes the aN accumulator init
    const f32x4 bN = { L2E2 * bhh[2 * H_ + uD + 0], L2E2 * bhh[2 * H_ + uD + 1],
                       L2E2 * bhh[2 * H_ + uD + 2], L2E2 * bhh[2 * H_ + uD + 3] };

    for (int i = t; i < R_ * H_; i += 512) hb0[i] = (f16)0.f;
    float hp0 = 0.f, hp1 = 0.f, hp2 = 0.f, hp3 = 0.f;

    // ---- coalesced output staging: thread -> (row, 4 contiguous units) ----
    const int orow = t >> 5;               // 0..15 (block-local row)
    const int oe4  = (t & 31) * 4;         // unit base 0..124
    const int oswz = (orow & 7) << 3;
    const int grow = rowBase + blockIdx.x * R_ + orow;
    float* op; size_t ost;
    if (oe4 < Co_) { op = outA + (size_t)grow * L_ * Co_ + oe4;            ost = Co_; }
    else           { op = outB + (size_t)grow * L_ * (H_ - Co_) + (oe4 - Co_); ost = H_ - Co_; }

    const int swzm = (c & 7) << 3;              // XOR swizzle mask (f16 index bits 3..5)
    const f16* gp = gi + (size_t)lrow * L_ * G3 + uD;

    // preload gi[0] into E buffers
    f16x4 gRe = *(const f16x4*)(gp + 0 * H_);
    f16x4 gZe = *(const f16x4*)(gp + 1 * H_);
    f16x4 gNe = *(const f16x4*)(gp + 2 * H_);
    f16x4 gRo, gZo, gNo;

    __syncthreads();

#define GRU_STEP(HCUR, HNEXT, GR, GZ, GN, DOSTAGE)                                  \
    {                                                                               \
        if (DOSTAGE) {  /* store h_out(prev step), coalesced, f16-rounded */        \
            f16x4 hv = *(const f16x4*)(HCUR + orow * H_ + (oe4 ^ oswz));            \
            f32x4 ov = {(float)hv[0], (float)hv[1], (float)hv[2], (float)hv[3]};    \
            *(f32x4*)op = ov;                                                       \
            op += ost;                                                              \
        }                                                                           \
        f16x8 hB0 = *(const f16x8*)(HCUR + c * H_ + ((q8 +  0) ^ swzm));            \
        f16x8 hB1 = *(const f16x8*)(HCUR + c * H_ + ((q8 + 32) ^ swzm));            \
        f16x8 hB2 = *(const f16x8*)(HCUR + c * H_ + ((q8 + 64) ^ swzm));            \
        f16x8 hB3 = *(const f16x8*)(HCUR + c * H_ + ((q8 + 96) ^ swzm));            \
        f32x4 aR = {(float)GR[0], (float)GR[1], (float)GR[2], (float)GR[3]};        \
        f32x4 aZ = {(float)GZ[0], (float)GZ[1], (float)GZ[2], (float)GZ[3]};        \
        f32x4 aN = bN;                                                              \
        aR = __builtin_amdgcn_mfma_f32_16x16x32_f16(WA[0][0], hB0, aR, 0, 0, 0);    \
        aZ = __builtin_amdgcn_mfma_f32_16x16x32_f16(WA[1][0], hB0, aZ, 0, 0, 0);    \
        aN = __builtin_amdgcn_mfma_f32_16x16x32_f16(WA[2][0], hB0, aN, 0, 0, 0);    \
        aR = __builtin_amdgcn_mfma_f32_16x16x32_f16(WA[0][1], hB1, aR, 0, 0, 0);    \
        aZ = __builtin_amdgcn_mfma_f32_16x16x32_f16(WA[1][1], hB1, aZ, 0, 0, 0);    \
        aN = __builtin_amdgcn_mfma_f32_16x16x32_f16(WA[2][1], hB1, aN, 0, 0, 0);    \
        aR = __builtin_amdgcn_mfma_f32_16x16x32_f16(WA[0][2], hB2, aR, 0, 0, 0);    \
        aZ = __builtin_amdgcn_mfma_f32_16x16x32_f16(WA[1][2], hB2, aZ, 0, 0, 0);    \
        aN = __builtin_amdgcn_mfma_f32_16x16x32_f16(WA[2][2], hB2, aN, 0, 0, 0);    \
        aR = __builtin_amdgcn_mfma_f32_16x16x32_f16(WA[0][3], hB3, aR, 0, 0, 0);    \
        aZ = __builtin_amdgcn_mfma_f32_16x16x32_f16(WA[1][3], hB3, aZ, 0, 0, 0);    \
        aN = __builtin_amdgcn_mfma_f32_16x16x32_f16(WA[2][3], hB3, aN, 0, 0, 0);    \
        float rg0 = __builtin_amdgcn_rcpf(1.f + __builtin_amdgcn_exp2f(-aR[0]));    \
        float rg1 = __builtin_amdgcn_rcpf(1.f + __builtin_amdgcn_exp2f(-aR[1]));    \
        float rg2 = __builtin_amdgcn_rcpf(1.f + __builtin_amdgcn_exp2f(-aR[2]));    \
        float rg3 = __builtin_amdgcn_rcpf(1.f + __builtin_amdgcn_exp2f(-aR[3]));    \
        float zg0 = __builtin_amdgcn_rcpf(1.f + __builtin_amdgcn_exp2f(-aZ[0]));    \
        float zg1 = __builtin_amdgcn_rcpf(1.f + __builtin_amdgcn_exp2f(-aZ[1]));    \
        float zg2 = __builtin_amdgcn_rcpf(1.f + __builtin_amdgcn_exp2f(-aZ[2]));    \
        float zg3 = __builtin_amdgcn_rcpf(1.f + __builtin_amdgcn_exp2f(-aZ[3]));    \
        float tn0 = fmaf(rg0, aN[0], (float)GN[0]);                                 \
        float tn1 = fmaf(rg1, aN[1], (float)GN[1]);                                 \
        float tn2 = fmaf(rg2, aN[2], (float)GN[2]);                                 \
        float tn3 = fmaf(rg3, aN[3], (float)GN[3]);                                 \
        float ng0 = fmaf(2.f, __builtin_amdgcn_rcpf(1.f + __builtin_amdgcn_exp2f(-tn0)), -1.f); \
        float ng1 = fmaf(2.f, __builtin_amdgcn_rcpf(1.f + __builtin_amdgcn_exp2f(-tn1)), -1.f); \
        float ng2 = fmaf(2.f, __builtin_amdgcn_rcpf(1.f + __builtin_amdgcn_exp2f(-tn2)), -1.f); \
        float ng3 = fmaf(2.f, __builtin_amdgcn_rcpf(1.f + __builtin_amdgcn_exp2f(-tn3)), -1.f); \
        hp0 = fmaf(zg0, hp0 - ng0, ng0);                                            \
        hp1 = fmaf(zg1, hp1 - ng1, ng1);                                            \
        hp2 = fmaf(zg2, hp2 - ng2, ng2);                                            \
        hp3 = fmaf(zg3, hp3 - ng3, ng3);                                            \
        f16x4 hv16 = {(f16)hp0, (f16)hp1, (f16)hp2, (f16)hp3};                      \
        *(f16x4*)(HNEXT + c * H_ + (uD ^ swzm)) = hv16;                             \
    }

    for (int l = 0; l < L_; l += 2) {
        // ---- even step l: read hb0, write hb1; prefetch gi[l+1] ----
        {
            const f16* gn = gp + (size_t)(l + 1) * G3;
            gRo = *(const f16x4*)(gn + 0 * H_);
            gZo = *(const f16x4*)(gn + 1 * H_);
            gNo = *(const f16x4*)(gn + 2 * H_);
        }
        GRU_STEP(hb0, hb1, gRe, gZe, gNe, (l > 0))
        __syncthreads();

        // ---- odd step l+1: read hb1, write hb0; prefetch gi[l+2] ----
        {
            int lp = (l + 2 < L_) ? (l + 2) : (L_ - 1);   // clamp: last reload unused
            const f16* gn = gp + (size_t)lp * G3;
            gRe = *(const f16x4*)(gn + 0 * H_);
            gZe = *(const f16x4*)(gn + 1 * H_);
            gNe = *(const f16x4*)(gn + 2 * H_);
        }
        GRU_STEP(hb1, hb0, gRo, gZo, gNo, true)
        __syncthreads();
    }
#undef GRU_STEP

    // final output: h_out(L-1) sits in hb0 (written by step 511), barrier already passed
    {
        f16x4 hv = *(const f16x4*)(hb0 + orow * H_ + (oe4 ^ oswz));
        f32x4 ov = {(float)hv[0], (float)hv[1], (float)hv[2], (float)hv[3]};
        *(f32x4*)op = ov;
    }
}

// ---------------- launch ----------------
extern "C" void kernel_launch(void* const* d_in, const int* in_sizes, int n_in,
                              void* d_out, int out_size, void* d_ws, size_t ws_size,
                              hipStream_t stream) {
    (void)in_sizes; (void)n_in;
    const float* cov = (const float*)d_in[0];
    const float* tr  = (const float*)d_in[1];
    const float* oc  = (const float*)d_in[2];
    const float* Wih = (const float*)d_in[3];
    const float* Whh = (const float*)d_in[4];
    const float* bih = (const float*)d_in[5];
    const float* bhh = (const float*)d_in[6];
    const float* g_t = (const float*)d_in[7];
    const float* bt  = (const float*)d_in[8];
    const float* g_o = (const float*)d_in[9];
    const float* bo  = (const float*)d_in[10];
    const float* g_c = (const float*)d_in[11];
    const float* bc  = (const float*)d_in[12];

    float* outA = (float*)d_out;
    float* outB = (float*)d_out + (size_t)B_ * L_ * Co_;

    // workspace layout: [WihH f16 384x96 | pad to 128KB | giH f16 (M_split x 384)]
    f16* WihH = (f16*)d_ws;
    f16* giH  = (f16*)((char*)d_ws + 131072);

    // normalized f16 input lives at the TOP of d_out (dead before outputs reach it)
    size_t outBytes = (size_t)out_size * 4;
    size_t ihBytes  = (size_t)B_ * L_ * KP * 2;   // 50.3 MB
    f16* inpH = (f16*)((char*)d_out + (outBytes - ihBytes));

    // pick batch split so gi fits in ws
    int S = 8;
    const int cand[4] = {1, 2, 4, 8};
    for (int i = 0; i < 4; i++) {
        size_t need = 131072 + ((size_t)B_ / cand[i]) * L_ * G3 * 2;
        if (need <= ws_size) { S = cand[i]; break; }
    }
    int Bs = B_ / S;

    k_prep_wih<<<dim3(144), dim3(256), 0, stream>>>(Wih, WihH);
    k_norm<<<dim3(B_), dim3(256), 0, stream>>>(cov, tr, oc, g_t, bt, g_o, bo, g_c, bc, inpH);

    for (int s = 0; s < S; s++) {
        const f16* Asub = inpH + (size_t)s * Bs * L_ * KP;
        int Msub = Bs * L_;
        k_gemm<<<dim3(Msub / 64), dim3(256), 0, stream>>>(Asub, WihH, bih, bhh, giH);
        k_scan_mfma<<<dim3(Bs / R_), dim3(512), 0, stream>>>(giH, Whh, bhh, outA, outB, s * Bs);
    }
}

// Round 5
// 584.787 us; speedup vs baseline: 1.5974x; 1.2699x over previous
//
#include <hip/hip_runtime.h>

typedef _Float16 f16;
typedef _Float16 f16x8 __attribute__((ext_vector_type(8)));
typedef _Float16 f16x4 __attribute__((ext_vector_type(4)));
typedef float f32x4 __attribute__((ext_vector_type(4)));

#define B_ 512
#define L_ 512
#define Cc_ 64
#define Ct_ 16
#define Co_ 8
#define H_ 128
#define IN_ 88
#define KP 96       // padded K for MFMA
#define G3 384      // 3*H
#define R_ 16       // batch rows per scan block / gemm tile

#define L2E  1.44269504088896f   // log2(e)
#define L2E2 2.88539008177793f   // 2*log2(e)

// Fragment-ordered gi: giF[g0][l][n0=0..23][q=0..3][c=0..15][e=0..3] (f16)
//   unit u = n0*16 + 4q + e, gate g = n0>>3, batch b = g0*16 + c.
// Per (g0,l): 24*256 f16 = 12KB. Scan lane (c,q,w) reads f16x4 wave-contiguous.

// ---------------- K0: W_ih -> A-fragment order (scaled); bias -> f32 (scaled, b_hh folded) ----
// WAf[((n0*3+ks)*64 + lane)*8 + j] = Wih'[unit = n0*16+(lane&15)][k = (lane>>4)*8+32ks+j]
__global__ void k_prep(const float* __restrict__ Wih,
                       const float* __restrict__ bih, const float* __restrict__ bhh,
                       f16* __restrict__ WAf, float* __restrict__ biasF) {
    int idx = blockIdx.x * 256 + threadIdx.x;
    if (idx < G3 * KP) {                       // 36864 WAf elements
        int n0 = idx / 1536;
        int rem = idx - n0 * 1536;
        int ks = rem >> 9;
        int rem2 = rem & 511;
        int lane = rem2 >> 3, j = rem2 & 7;
        int unit = n0 * 16 + (lane & 15);
        int k = ((lane >> 4) << 3) + 32 * ks + j;
        float s = (n0 < 16) ? L2E : L2E2;
        WAf[idx] = (k < IN_) ? (f16)(Wih[unit * IN_ + k] * s) : (f16)0.f;
    } else if (idx < G3 * KP + G3) {           // 384 biases
        int u = idx - G3 * KP;
        biasF[u] = (u < 256) ? (bih[u] + bhh[u]) * L2E : bih[u] * L2E2;
    }
}

// ---------------- K1: time-norm + concat -> f16, TRANSPOSED [g0][l][c][96] ----------------
__global__ __launch_bounds__(256) void k_norm(
        const float* __restrict__ cov, const float* __restrict__ tr, const float* __restrict__ oc,
        const float* __restrict__ g_t, const float* __restrict__ bt,
        const float* __restrict__ g_o, const float* __restrict__ bo,
        const float* __restrict__ g_c, const float* __restrict__ bc,
        f16* __restrict__ inpT) {
    int b = blockIdx.x, t = threadIdx.x;
    __shared__ float ps[256], ps2[256];
    __shared__ float sc[88], sh[88];   // concat order: t[0:16), o[16:24), c[24:88)

    { // covariates, C=64, 4 l-groups
        int c = t & 63, lg = t >> 6;
        const float* p = cov + (size_t)b * L_ * Cc_ + c;
        float s = 0.f, s2 = 0.f;
        for (int i = lg; i < L_; i += 4) { float v = p[(size_t)i * Cc_]; s += v; s2 += v * v; }
        ps[t] = s; ps2[t] = s2; __syncthreads();
        if (t < 64) {
            float S = 0.f, S2 = 0.f;
            for (int g = 0; g < 4; g++) { S += ps[t + 64 * g]; S2 += ps2[t + 64 * g]; }
            float m = S * (1.f / L_), v = S2 * (1.f / L_) - m * m;
            float inv = rsqrtf(v + 1e-5f);
            float gg = g_c[t] * inv;
            sc[24 + t] = gg; sh[24 + t] = bc[t] - m * gg;
        }
        __syncthreads();
    }
    { // treatments, C=16, 16 l-groups
        int c = t & 15, lg = t >> 4;
        const float* p = tr + (size_t)b * L_ * Ct_ + c;
        float s = 0.f, s2 = 0.f;
        for (int i = lg; i < L_; i += 16) { float v = p[(size_t)i * Ct_]; s += v; s2 += v * v; }
        ps[t] = s; ps2[t] = s2; __syncthreads();
        if (t < 16) {
            float S = 0.f, S2 = 0.f;
            for (int g = 0; g < 16; g++) { S += ps[t + 16 * g]; S2 += ps2[t + 16 * g]; }
            float m = S * (1.f / L_), v = S2 * (1.f / L_) - m * m;
            float inv = rsqrtf(v + 1e-5f);
            float gg = g_t[t] * inv;
            sc[t] = gg; sh[t] = bt[t] - m * gg;
        }
        __syncthreads();
    }
    { // outcomes, C=8, 32 l-groups
        int c = t & 7, lg = t >> 3;
        const float* p = oc + (size_t)b * L_ * Co_ + c;
        float s = 0.f, s2 = 0.f;
        for (int i = lg; i < L_; i += 32) { float v = p[(size_t)i * Co_]; s += v; s2 += v * v; }
        ps[t] = s; ps2[t] = s2; __syncthreads();
        if (t < 8) {
            float S = 0.f, S2 = 0.f;
            for (int g = 0; g < 32; g++) { S += ps[t + 8 * g]; S2 += ps2[t + 8 * g]; }
            float m = S * (1.f / L_), v = S2 * (1.f / L_) - m * m;
            float inv = rsqrtf(v + 1e-5f);
            float gg = g_o[t] * inv;
            sc[16 + t] = gg; sh[16 + t] = bo[t] - m * gg;
        }
        __syncthreads();
    }
    // phase B: normalize + concat + pad -> inpT[((b>>4)*512 + l)*16 + (b&15)][96]
    f16* outp = inpT + ((size_t)(b >> 4) * L_ * 16 + (b & 15)) * KP;
    for (int idx = t; idx < L_ * KP; idx += 256) {
        int l = idx / KP, cc = idx % KP;
        float y = 0.f;
        if (cc < 88) {
            float x;
            if (cc < 16)      x = tr[((size_t)b * L_ + l) * Ct_ + cc];
            else if (cc < 24) x = oc[((size_t)b * L_ + l) * Co_ + (cc - 16)];
            else              x = cov[((size_t)b * L_ + l) * Cc_ + (cc - 24)];
            y = x * sc[cc] + sh[cc];
        }
        outp[(size_t)l * 16 * KP + cc] = (f16)y;
    }
}

// ---------------- K2: gi GEMM, fragment-ordered output. ---------------------------------
// Block = (g0, 4 l's), wave = one l. A = W-fragments (coalesced from WAf),
// B = x-fragments (lane c = batch-in-group, 16-seg amortized over 24 tiles).
// D: row = unit(4q+e), col = batch(c)  == scan's MFMA layout. Store: 512B/wave contig.
__global__ __launch_bounds__(256) void k_gemm(
        const f16* __restrict__ inpT, const f16* __restrict__ WAf,
        const float* __restrict__ biasF, f16* __restrict__ giF) {
    const int g0 = blockIdx.x >> 7;
    const int l  = ((blockIdx.x & 127) << 2) + (threadIdx.x >> 6);
    const int lane = threadIdx.x & 63;
    const int c = lane & 15, q = lane >> 4;

    const f16* bp = inpT + (((size_t)g0 * L_ + l) * 16 + c) * KP + q * 8;
    f16x8 x0 = *(const f16x8*)(bp);
    f16x8 x1 = *(const f16x8*)(bp + 32);
    f16x8 x2 = *(const f16x8*)(bp + 64);

    const f16x8* wa = (const f16x8*)WAf;
    f16* gout = giF + ((size_t)g0 * L_ + l) * 24 * 256 + q * 64 + c * 4;

    #pragma unroll 4
    for (int n0 = 0; n0 < 24; n0++) {
        f16x8 a0 = wa[(n0 * 3 + 0) * 64 + lane];
        f16x8 a1 = wa[(n0 * 3 + 1) * 64 + lane];
        f16x8 a2 = wa[(n0 * 3 + 2) * 64 + lane];
        f32x4 acc = *(const f32x4*)(biasF + n0 * 16 + q * 4);
        acc = __builtin_amdgcn_mfma_f32_16x16x32_f16(a0, x0, acc, 0, 0, 0);
        acc = __builtin_amdgcn_mfma_f32_16x16x32_f16(a1, x1, acc, 0, 0, 0);
        acc = __builtin_amdgcn_mfma_f32_16x16x32_f16(a2, x2, acc, 0, 0, 0);
        f16x4 st = {(f16)acc[0], (f16)acc[1], (f16)acc[2], (f16)acc[3]};
        *(f16x4*)(gout + n0 * 256) = st;
    }
}

// ---------------- K3: GRU scan via MFMA. 16 rows/block, 8 waves. ------------------------
__global__ __launch_bounds__(512, 2) void k_scan_mfma(
        const f16* __restrict__ giF, const float* __restrict__ Whh, const float* __restrict__ bhh,
        float* __restrict__ outA, float* __restrict__ outB, int rowBase) {
    const int t = threadIdx.x;
    const int w = t >> 6;          // wave 0..7: owns hidden units [16w, 16w+16)
    const int lane = t & 63;
    const int c = lane & 15;       // batch row within tile
    const int q = lane >> 4;       // 0..3
    const int q8 = q * 8;
    const int uD = 16 * w + q * 4;              // this lane's unit base in D

    __shared__ f16 hb0[R_ * H_];                // 4KB each, swizzled [b][k^((b&7)<<3)]
    __shared__ f16 hb1[R_ * H_];

    // persistent W_hh A-fragments: unit = 16w + c, k = q*8 + 32ks + j  (f32 -> f16, scaled)
    f16x8 WA[3][4];
    #pragma unroll
    for (int g = 0; g < 3; g++) {
        float s = (g < 2) ? L2E : L2E2;
        #pragma unroll
        for (int ks = 0; ks < 4; ks++) {
            const float* wp = Whh + (size_t)(g * H_ + 16 * w + c) * H_ + q8 + 32 * ks;
            f16x8 v;
            #pragma unroll
            for (int j = 0; j < 8; j++) v[j] = (f16)(wp[j] * s);
            WA[g][ks] = v;
        }
    }
    // n-gate b_hh, pre-scaled — becomes the aN accumulator init
    const f32x4 bN = { L2E2 * bhh[2 * H_ + uD + 0], L2E2 * bhh[2 * H_ + uD + 1],
                       L2E2 * bhh[2 * H_ + uD + 2], L2E2 * bhh[2 * H_ + uD + 3] };

    for (int i = t; i < R_ * H_; i += 512) hb0[i] = (f16)0.f;
    float hp0 = 0.f, hp1 = 0.f, hp2 = 0.f, hp3 = 0.f;

    // ---- coalesced output staging: thread -> (row, 4 contiguous units) ----
    const int orow = t >> 5;               // 0..15 (block-local row)
    const int oe4  = (t & 31) * 4;         // unit base 0..124
    const int oswz = (orow & 7) << 3;
    const int grow = rowBase + blockIdx.x * R_ + orow;
    float* op; size_t ost;
    if (oe4 < Co_) { op = outA + (size_t)grow * L_ * Co_ + oe4;            ost = Co_; }
    else           { op = outB + (size_t)grow * L_ * (H_ - Co_) + (oe4 - Co_); ost = H_ - Co_; }

    const int swzm = (c & 7) << 3;              // XOR swizzle mask (f16 index bits 3..5)
    // fragment-ordered gi pointer: wave-contiguous 512B loads
    const f16* gbase = giF + (size_t)blockIdx.x * L_ * 24 * 256 + w * 256 + q * 64 + c * 4;

    // preload gi[0] into E buffers
    f16x4 gRe = *(const f16x4*)(gbase + 0 * 2048);
    f16x4 gZe = *(const f16x4*)(gbase + 1 * 2048);
    f16x4 gNe = *(const f16x4*)(gbase + 2 * 2048);
    f16x4 gRo, gZo, gNo;

    __syncthreads();

#define GRU_STEP(HCUR, HNEXT, GR, GZ, GN, DOSTAGE)                                  \
    {                                                                               \
        if (DOSTAGE) {  /* store h_out(prev step), coalesced, f16-rounded */        \
            f16x4 hv = *(const f16x4*)(HCUR + orow * H_ + (oe4 ^ oswz));            \
            f32x4 ov = {(float)hv[0], (float)hv[1], (float)hv[2], (float)hv[3]};    \
            *(f32x4*)op = ov;                                                       \
            op += ost;                                                              \
        }                                                                           \
        f16x8 hB0 = *(const f16x8*)(HCUR + c * H_ + ((q8 +  0) ^ swzm));            \
        f16x8 hB1 = *(const f16x8*)(HCUR + c * H_ + ((q8 + 32) ^ swzm));            \
        f16x8 hB2 = *(const f16x8*)(HCUR + c * H_ + ((q8 + 64) ^ swzm));            \
        f16x8 hB3 = *(const f16x8*)(HCUR + c * H_ + ((q8 + 96) ^ swzm));            \
        f32x4 aR = {(float)GR[0], (float)GR[1], (float)GR[2], (float)GR[3]};        \
        f32x4 aZ = {(float)GZ[0], (float)GZ[1], (float)GZ[2], (float)GZ[3]};        \
        f32x4 aN = bN;                                                              \
        aR = __builtin_amdgcn_mfma_f32_16x16x32_f16(WA[0][0], hB0, aR, 0, 0, 0);    \
        aZ = __builtin_amdgcn_mfma_f32_16x16x32_f16(WA[1][0], hB0, aZ, 0, 0, 0);    \
        aN = __builtin_amdgcn_mfma_f32_16x16x32_f16(WA[2][0], hB0, aN, 0, 0, 0);    \
        aR = __builtin_amdgcn_mfma_f32_16x16x32_f16(WA[0][1], hB1, aR, 0, 0, 0);    \
        aZ = __builtin_amdgcn_mfma_f32_16x16x32_f16(WA[1][1], hB1, aZ, 0, 0, 0);    \
        aN = __builtin_amdgcn_mfma_f32_16x16x32_f16(WA[2][1], hB1, aN, 0, 0, 0);    \
        aR = __builtin_amdgcn_mfma_f32_16x16x32_f16(WA[0][2], hB2, aR, 0, 0, 0);    \
        aZ = __builtin_amdgcn_mfma_f32_16x16x32_f16(WA[1][2], hB2, aZ, 0, 0, 0);    \
        aN = __builtin_amdgcn_mfma_f32_16x16x32_f16(WA[2][2], hB2, aN, 0, 0, 0);    \
        aR = __builtin_amdgcn_mfma_f32_16x16x32_f16(WA[0][3], hB3, aR, 0, 0, 0);    \
        aZ = __builtin_amdgcn_mfma_f32_16x16x32_f16(WA[1][3], hB3, aZ, 0, 0, 0);    \
        aN = __builtin_amdgcn_mfma_f32_16x16x32_f16(WA[2][3], hB3, aN, 0, 0, 0);    \
        float rg0 = __builtin_amdgcn_rcpf(1.f + __builtin_amdgcn_exp2f(-aR[0]));    \
        float rg1 = __builtin_amdgcn_rcpf(1.f + __builtin_amdgcn_exp2f(-aR[1]));    \
        float rg2 = __builtin_amdgcn_rcpf(1.f + __builtin_amdgcn_exp2f(-aR[2]));    \
        float rg3 = __builtin_amdgcn_rcpf(1.f + __builtin_amdgcn_exp2f(-aR[3]));    \
        float zg0 = __builtin_amdgcn_rcpf(1.f + __builtin_amdgcn_exp2f(-aZ[0]));    \
        float zg1 = __builtin_amdgcn_rcpf(1.f + __builtin_amdgcn_exp2f(-aZ[1]));    \
        float zg2 = __builtin_amdgcn_rcpf(1.f + __builtin_amdgcn_exp2f(-aZ[2]));    \
        float zg3 = __builtin_amdgcn_rcpf(1.f + __builtin_amdgcn_exp2f(-aZ[3]));    \
        float tn0 = fmaf(rg0, aN[0], (float)GN[0]);                                 \
        float tn1 = fmaf(rg1, aN[1], (float)GN[1]);                                 \
        float tn2 = fmaf(rg2, aN[2], (float)GN[2]);                                 \
        float tn3 = fmaf(rg3, aN[3], (float)GN[3]);                                 \
        float ng0 = fmaf(2.f, __builtin_amdgcn_rcpf(1.f + __builtin_amdgcn_exp2f(-tn0)), -1.f); \
        float ng1 = fmaf(2.f, __builtin_amdgcn_rcpf(1.f + __builtin_amdgcn_exp2f(-tn1)), -1.f); \
        float ng2 = fmaf(2.f, __builtin_amdgcn_rcpf(1.f + __builtin_amdgcn_exp2f(-tn2)), -1.f); \
        float ng3 = fmaf(2.f, __builtin_amdgcn_rcpf(1.f + __builtin_amdgcn_exp2f(-tn3)), -1.f); \
        hp0 = fmaf(zg0, hp0 - ng0, ng0);                                            \
        hp1 = fmaf(zg1, hp1 - ng1, ng1);                                            \
        hp2 = fmaf(zg2, hp2 - ng2, ng2);                                            \
        hp3 = fmaf(zg3, hp3 - ng3, ng3);                                            \
        f16x4 hv16 = {(f16)hp0, (f16)hp1, (f16)hp2, (f16)hp3};                      \
        *(f16x4*)(HNEXT + c * H_ + (uD ^ swzm)) = hv16;                             \
    }

    for (int l = 0; l < L_; l += 2) {
        // ---- even step l: read hb0, write hb1; prefetch gi[l+1] (contiguous/wave) ----
        {
            const f16* gn = gbase + (size_t)(l + 1) * 6144;
            gRo = *(const f16x4*)(gn + 0 * 2048);
            gZo = *(const f16x4*)(gn + 1 * 2048);
            gNo = *(const f16x4*)(gn + 2 * 2048);
        }
        GRU_STEP(hb0, hb1, gRe, gZe, gNe, (l > 0))
        __syncthreads();

        // ---- odd step l+1: read hb1, write hb0; prefetch gi[l+2] ----
        {
            int lp = (l + 2 < L_) ? (l + 2) : (L_ - 1);   // clamp: last reload unused
            const f16* gn = gbase + (size_t)lp * 6144;
            gRe = *(const f16x4*)(gn + 0 * 2048);
            gZe = *(const f16x4*)(gn + 1 * 2048);
            gNe = *(const f16x4*)(gn + 2 * 2048);
        }
        GRU_STEP(hb1, hb0, gRo, gZo, gNo, true)
        __syncthreads();
    }
#undef GRU_STEP

    // final output: h_out(L-1) sits in hb0 (written by step 511), barrier already passed
    {
        f16x4 hv = *(const f16x4*)(hb0 + orow * H_ + (oe4 ^ oswz));
        f32x4 ov = {(float)hv[0], (float)hv[1], (float)hv[2], (float)hv[3]};
        *(f32x4*)op = ov;
    }
}

// ---------------- launch ----------------
extern "C" void kernel_launch(void* const* d_in, const int* in_sizes, int n_in,
                              void* d_out, int out_size, void* d_ws, size_t ws_size,
                              hipStream_t stream) {
    (void)in_sizes; (void)n_in;
    const float* cov = (const float*)d_in[0];
    const float* tr  = (const float*)d_in[1];
    const float* oc  = (const float*)d_in[2];
    const float* Wih = (const float*)d_in[3];
    const float* Whh = (const float*)d_in[4];
    const float* bih = (const float*)d_in[5];
    const float* bhh = (const float*)d_in[6];
    const float* g_t = (const float*)d_in[7];
    const float* bt  = (const float*)d_in[8];
    const float* g_o = (const float*)d_in[9];
    const float* bo  = (const float*)d_in[10];
    const float* g_c = (const float*)d_in[11];
    const float* bc  = (const float*)d_in[12];

    float* outA = (float*)d_out;
    float* outB = (float*)d_out + (size_t)B_ * L_ * Co_;

    // workspace: [WAf 72KB | biasF 1.5KB | pad to 128KB | giF f16 (Bs*512*384)]
    f16*   WAf   = (f16*)d_ws;
    float* biasF = (float*)((char*)d_ws + 73728);
    f16*   giF   = (f16*)((char*)d_ws + 131072);

    // normalized f16 input (transposed) lives at the TOP of d_out
    size_t outBytes = (size_t)out_size * 4;
    size_t ihBytes  = (size_t)B_ * L_ * KP * 2;   // 50.3 MB
    f16* inpT = (f16*)((char*)d_out + (outBytes - ihBytes));

    // pick batch split so giF fits in ws
    int S = 8;
    const int cand[4] = {1, 2, 4, 8};
    for (int i = 0; i < 4; i++) {
        size_t need = 131072 + ((size_t)B_ / cand[i]) * L_ * G3 * 2;
        if (need <= ws_size) { S = cand[i]; break; }
    }
    int Bs = B_ / S;

    k_prep<<<dim3(146), dim3(256), 0, stream>>>(Wih, bih, bhh, WAf, biasF);
    k_norm<<<dim3(B_), dim3(256), 0, stream>>>(cov, tr, oc, g_t, bt, g_o, bo, g_c, bc, inpT);

    for (int s = 0; s < S; s++) {
        const f16* Asub = inpT + (size_t)s * Bs * L_ * KP;
        k_gemm<<<dim3((Bs / 16) * 128), dim3(256), 0, stream>>>(Asub, WAf, biasF, giF);
        k_scan_mfma<<<dim3(Bs / R_), dim3(512), 0, stream>>>(giF, Whh, bhh, outA, outB, s * Bs);
    }
}